// Round 6
// baseline (4123.880 us; speedup 1.0000x reference)
//
#include <hip/hip_runtime.h>

#define PER  149796
#define NN   1048573          // 1 + 7*PER
#define HDIM 64
#define EDIM 32
#define NIOU 192

typedef _Float16 f16;
typedef _Float16 f16x8 __attribute__((ext_vector_type(8)));
typedef _Float16 f16x4 __attribute__((ext_vector_type(4)));
typedef float    f32x4 __attribute__((ext_vector_type(4)));

__device__ __forceinline__ float sigf(float x){ return 1.0f/(1.0f+__expf(-x)); }
__device__ __forceinline__ float tanh_f(float x){
  float ax = fabsf(x);
  float e  = __expf(-2.0f*ax);
  float t  = (1.0f - e)/(1.0f + e);
  return x < 0.0f ? -t : t;
}

// ================= CSR build: counts -> scan -> scatter =================
__global__ __launch_bounds__(256) void count_kernel(const int* __restrict__ parent, int* __restrict__ cnt){
  int i = blockIdx.x*256 + threadIdx.x;
  if (i >= 1 && i < NN) atomicAdd(&cnt[parent[i]], 1);
}

__global__ __launch_bounds__(256) void scan1_kernel(const int* __restrict__ cnt, int* __restrict__ bsum){
  __shared__ int sc[256];
  int b = blockIdx.x, t = threadIdx.x;
  int base = b*1024 + t*4;
  int s = 0;
  #pragma unroll
  for (int e=0;e<4;e++){ int idx=base+e; if (idx<NN) s += cnt[idx]; }
  sc[t]=s; __syncthreads();
  for (int d=128; d>0; d>>=1){ if (t<d) sc[t]+=sc[t+d]; __syncthreads(); }
  if (t==0) bsum[b]=sc[0];
}

__global__ __launch_bounds__(1024) void scan2_kernel(const int* __restrict__ bsum, int* __restrict__ bbase){
  __shared__ int sc[1024];
  int t=threadIdx.x;
  sc[t]=bsum[t]; __syncthreads();
  for (int d=1; d<1024; d<<=1){
    int v = (t>=d)? sc[t-d] : 0; __syncthreads();
    sc[t]+=v; __syncthreads();
  }
  bbase[t] = (t==0)?0:sc[t-1];
}

__global__ __launch_bounds__(256) void scan3_kernel(const int* __restrict__ cnt, const int* __restrict__ bbase,
                                                    int* __restrict__ off, int* __restrict__ cursor){
  __shared__ int sc[256];
  int b=blockIdx.x, t=threadIdx.x;
  int base=b*1024+t*4;
  int e0 = (base  <NN)?cnt[base  ]:0;
  int e1 = (base+1<NN)?cnt[base+1]:0;
  int e2 = (base+2<NN)?cnt[base+2]:0;
  int e3 = (base+3<NN)?cnt[base+3]:0;
  int tsum=e0+e1+e2+e3;
  sc[t]=tsum; __syncthreads();
  for (int d=1; d<256; d<<=1){
    int v=(t>=d)?sc[t-d]:0; __syncthreads();
    sc[t]+=v; __syncthreads();
  }
  int x = bbase[b] + ((t==0)?0:sc[t-1]);
  if (base  <NN){ off[base  ]=x;          cursor[base  ]=x; }
  if (base+1<NN){ off[base+1]=x+e0;       cursor[base+1]=x+e0; }
  if (base+2<NN){ off[base+2]=x+e0+e1;    cursor[base+2]=x+e0+e1; }
  if (base+3<NN){ off[base+3]=x+e0+e1+e2; cursor[base+3]=x+e0+e1+e2; }
}

__global__ __launch_bounds__(256) void scatter_kernel(const int* __restrict__ parent, const int* __restrict__ tok,
    int* __restrict__ cursor, int* __restrict__ childpos, int* __restrict__ ptok){
  int i = blockIdx.x*256+threadIdx.x;
  if (i < 1 || i >= NN) return;
  int jp = parent[i];
  int pos = atomicAdd(&cursor[jp], 1);
  childpos[i] = pos;
  ptok[pos] = tok[jp];
}

// ================= weight tables / MFMA packs =================
__global__ __launch_bounds__(256) void table_kernel(
    const float* __restrict__ emb, const float* __restrict__ Wiou, const float* __restrict__ biou,
    const float* __restrict__ Wf, const float* __restrict__ bf,
    float* __restrict__ embWiou, float* __restrict__ embWf)
{
  int v = blockIdx.x;
  int m = threadIdx.x;
  const float* x = emb + (size_t)v*EDIM;
  if (m < NIOU){
    float a = biou[m];
    #pragma unroll
    for (int e=0;e<EDIM;e++) a += Wiou[m*EDIM+e]*x[e];
    embWiou[(size_t)v*NIOU + m] = a;
  } else {
    int mm = m - NIOU;
    float a = bf[mm];
    #pragma unroll
    for (int e=0;e<EDIM;e++) a += Wf[mm*EDIM+e]*x[e];
    embWf[(size_t)v*HDIM + mm] = a;
  }
}

// B-frag order for mfma_f32_16x16x32_f16 (verified R4): lane L: n=t*16+(L&15), k=s*32+(L>>4)*8+j
__global__ void pack_kernel(const float* __restrict__ Uf, const float* __restrict__ Uiou,
                            f16* __restrict__ Bf, f16* __restrict__ Biou)
{
  for (int i = threadIdx.x; i < 2*4*64*8; i += 256){
    int j = i & 7, L = (i>>3)&63, st = i>>9;
    int t = st & 3, s = st >> 2;
    int k = s*32 + (L>>4)*8 + j;
    int n = t*16 + (L&15);
    Bf[i] = (f16)Uf[n*HDIM + k];
  }
  for (int i = threadIdx.x; i < 2*12*64*8; i += 256){
    int j = i & 7, L = (i>>3)&63, st = i>>9;
    int t = st % 12, s = st / 12;
    int k = s*32 + (L>>4)*8 + j;
    int n = t*16 + (L&15);
    Biou[i] = (f16)Uiou[n*HDIM + k];
  }
}

// ================= leaves =================
// leafA: elementwise h,c written at LEVEL-RELATIVE sorted position (global pos - 6*PER)
__global__ __launch_bounds__(256) void leafA_kernel(
    const int* __restrict__ tok, const int* __restrict__ childpos,
    const float* __restrict__ embWiou, f16* __restrict__ Hout, float* __restrict__ Ctmp)
{
  int gid = blockIdx.x*256 + threadIdx.x;
  if (gid >= PER*16) return;
  int j = gid >> 4, sub = gid & 15;
  int g = 1 + 6*PER + j;
  int t = tok[g];
  const float* row = embWiou + (size_t)t*NIOU;
  float4 i4 = *(const float4*)(row + sub*4);
  float4 o4 = *(const float4*)(row + 64 + sub*4);
  float4 u4 = *(const float4*)(row + 128 + sub*4);
  float4 cv; f16x4 hv;
  cv.x = sigf(i4.x)*tanh_f(u4.x); hv.x = (f16)(sigf(o4.x)*tanh_f(cv.x));
  cv.y = sigf(i4.y)*tanh_f(u4.y); hv.y = (f16)(sigf(o4.y)*tanh_f(cv.y));
  cv.z = sigf(i4.z)*tanh_f(u4.z); hv.z = (f16)(sigf(o4.z)*tanh_f(cv.z));
  cv.w = sigf(i4.w)*tanh_f(u4.w); hv.w = (f16)(sigf(o4.w)*tanh_f(cv.w));
  int pos = childpos[g] - 6*PER;          // relative leaf position in [0, PER)
  *(float4*)(Ctmp + (size_t)pos*HDIM + sub*4) = cv;
  *(f16x4*)(Hout + (size_t)pos*HDIM + sub*4) = hv;
}

// leafB: FC for leaf level, streaming rel rows [0,PER); ptok indexed globally (6*PER + row)
__global__ __launch_bounds__(256) void leafB_kernel(
    const int* __restrict__ ptok, const float* __restrict__ embWf, const f16* __restrict__ Ufpack,
    const f16* __restrict__ Hin, const float* __restrict__ Ctmp, float* __restrict__ FCout)
{
  int lane = threadIdx.x & 63;
  int wv   = threadIdx.x >> 6;
  int base = (blockIdx.x*4 + wv)*64;
  if (base >= PER) return;
  int q = lane >> 4, c16 = lane & 15;
  const f16x8* Bp = (const f16x8*)Ufpack;
  f16x8 B[2][4];
  #pragma unroll
  for (int s=0;s<2;s++)
    #pragma unroll
    for (int t=0;t<4;t++) B[s][t] = Bp[(s*4+t)*64 + lane];
  f32x4 acc[4][4];
  #pragma unroll
  for (int a=0;a<4;a++)
    #pragma unroll
    for (int b=0;b<4;b++) acc[a][b] = (f32x4){0.f,0.f,0.f,0.f};
  #pragma unroll
  for (int tm=0;tm<4;tm++){
    int r0 = base + tm*16 + c16;
    if (r0 > PER-1) r0 = PER-1;
    const f16* hp = Hin + (size_t)r0*HDIM;
    f16x8 A0 = *(const f16x8*)(hp + q*8);
    f16x8 A1 = *(const f16x8*)(hp + 32 + q*8);
    #pragma unroll
    for (int nt=0;nt<4;nt++){
      acc[tm][nt] = __builtin_amdgcn_mfma_f32_16x16x32_f16(A0, B[0][nt], acc[tm][nt], 0,0,0);
      acc[tm][nt] = __builtin_amdgcn_mfma_f32_16x16x32_f16(A1, B[1][nt], acc[tm][nt], 0,0,0);
    }
  }
  #pragma unroll
  for (int tm=0;tm<4;tm++){
    #pragma unroll
    for (int r=0;r<4;r++){
      int lrow = base + tm*16 + q*4 + r;
      bool ok = lrow < PER;
      int rl = ok ? lrow : PER-1;
      int wt = ptok[6*PER + rl];
      const float* wr = embWf + (size_t)wt*HDIM;
      #pragma unroll
      for (int nt=0;nt<4;nt++){
        int col = nt*16 + c16;
        float gg = acc[tm][nt][r] + wr[col];
        float v = sigf(gg) * Ctmp[(size_t)rl*HDIM + col];
        if (ok) FCout[(size_t)rl*HDIM + col] = v;
      }
    }
  }
}

// ================= fused node kernel =================
// phase1: segmented streaming sum of children (rel rows in Hin/FCin) -> Ah(f16), FAs
// phase2: MFMA Hsum @ Uiou^T + activation epilogue -> c,h; h written to Hout[childpos-outbase]
// phase3: h -> LDS -> A-frags -> MFMA Uf -> FC -> FCout[childpos-outbase]
__global__ __launch_bounds__(256) void node_fused(
    const int* __restrict__ tok, const int* __restrict__ off,
    const int* __restrict__ childpos, const int* __restrict__ ptok,
    const float* __restrict__ embWiou, const float* __restrict__ embWf,
    const f16* __restrict__ Biopack, const f16* __restrict__ Ufpack,
    const f16* __restrict__ Hin, const float* __restrict__ FCin,
    f16* __restrict__ Hout, float* __restrict__ FCout,
    int poff, int relbase, int outbase)
{
  __shared__ f16   Ah[64*72];
  __shared__ float FAs[64*68];
  int lane = threadIdx.x & 63;
  int wv   = __builtin_amdgcn_readfirstlane(threadIdx.x >> 6);
  int p0   = wv*16;
  int j0   = blockIdx.x*64 + p0;
  // ---- phase 1: segmented stream-sum over rel child rows
  int pCur = off[poff + ((j0 < PER) ? j0 : (PER-1))] - relbase;
  #pragma unroll 1
  for (int i=0;i<16;i++){
    int j = j0 + i;
    float hs = 0.f, fa = 0.f;
    if (j < PER){
      int pEnd = off[poff + j + 1] - relbase;
      for (int p=pCur; p<pEnd; ++p){
        hs += (float)Hin[(size_t)p*HDIM + lane];
        fa += FCin[(size_t)p*HDIM + lane];
      }
      pCur = pEnd;
    }
    Ah[(p0+i)*72 + lane] = (f16)hs;
    FAs[(p0+i)*68 + lane] = fa;
  }
  __syncthreads();
  // ---- phase 2: iou MFMA + epilogue
  int q = lane>>4, c16 = lane&15;
  f16x8 A0 = *(const f16x8*)(Ah + (p0+c16)*72 + q*8);
  f16x8 A1 = *(const f16x8*)(Ah + (p0+c16)*72 + 32 + q*8);
  const f16x8* Bp = (const f16x8*)Biopack;
  f32x4 acc[12];
  #pragma unroll
  for (int nt=0;nt<12;nt++) acc[nt] = (f32x4){0.f,0.f,0.f,0.f};
  #pragma unroll
  for (int nt=0;nt<12;nt++){
    f16x8 B0 = Bp[nt*64 + lane];
    f16x8 B1 = Bp[(12+nt)*64 + lane];
    acc[nt] = __builtin_amdgcn_mfma_f32_16x16x32_f16(A0, B0, acc[nt], 0,0,0);
    acc[nt] = __builtin_amdgcn_mfma_f32_16x16x32_f16(A1, B1, acc[nt], 0,0,0);
  }
  float cc[4][4];
  f16   hh[4][4];
  int   opos_[4]; int wt_[4]; bool ok_[4];
  #pragma unroll
  for (int r=0;r<4;r++){
    int j = j0 + q*4 + r;
    bool ok = j < PER;
    int jl = ok ? j : PER-1;
    int g = poff + jl;
    int tk = tok[g];
    const float* tr = embWiou + (size_t)tk*NIOU;
    int opg = childpos[g];                  // global pos of this node as a child
    int op  = opg - outbase;                // relative row in Hout/FCout
    opos_[r]=op; ok_[r]=ok; wt_[r]=ptok[opg];
    int prow = p0 + q*4 + r;
    #pragma unroll
    for (int nt=0;nt<4;nt++){
      int col = nt*16 + c16;
      float ai = acc[nt][r]   + tr[col];
      float ao = acc[nt+4][r] + tr[64+col];
      float au = acc[nt+8][r] + tr[128+col];
      float fa = FAs[prow*68 + col];
      float c = sigf(ai)*tanh_f(au) + fa;
      float h = sigf(ao)*tanh_f(c);
      cc[r][nt] = c;
      hh[r][nt] = (f16)h;
      if (ok) Hout[(size_t)op*HDIM + col] = (f16)h;
    }
  }
  __syncthreads();                 // all phase-2 LDS reads done
  // ---- phase 3: h -> Ah, Uf MFMA, FC
  #pragma unroll
  for (int r=0;r<4;r++)
    #pragma unroll
    for (int nt=0;nt<4;nt++)
      Ah[(p0+q*4+r)*72 + nt*16 + c16] = hh[r][nt];
  __syncthreads();
  f16x8 H0 = *(const f16x8*)(Ah + (p0+c16)*72 + q*8);
  f16x8 H1 = *(const f16x8*)(Ah + (p0+c16)*72 + 32 + q*8);
  const f16x8* Up = (const f16x8*)Ufpack;
  f32x4 g4[4];
  #pragma unroll
  for (int nt=0;nt<4;nt++) g4[nt] = (f32x4){0.f,0.f,0.f,0.f};
  #pragma unroll
  for (int nt=0;nt<4;nt++){
    f16x8 B0 = Up[nt*64 + lane];
    f16x8 B1 = Up[(4+nt)*64 + lane];
    g4[nt] = __builtin_amdgcn_mfma_f32_16x16x32_f16(H0, B0, g4[nt], 0,0,0);
    g4[nt] = __builtin_amdgcn_mfma_f32_16x16x32_f16(H1, B1, g4[nt], 0,0,0);
  }
  #pragma unroll
  for (int r=0;r<4;r++){
    if (!ok_[r]) continue;
    const float* wr = embWf + (size_t)wt_[r]*HDIM;
    int op = opos_[r];
    #pragma unroll
    for (int nt=0;nt<4;nt++){
      int col = nt*16 + c16;
      float v = sigf(g4[nt][r] + wr[col]) * cc[r][nt];
      FCout[(size_t)op*HDIM + col] = v;
    }
  }
}

// ================= root =================
__global__ __launch_bounds__(256) void rootred_kernel(
    const float* __restrict__ FCin, const f16* __restrict__ Hin, float* __restrict__ rootacc)
{
  int t = blockIdx.x*blockDim.x + threadIdx.x;
  int m = t & 63;
  int j0 = t >> 6;
  int jstep = (gridDim.x*blockDim.x) >> 6;
  float af=0.f, ah=0.f;
  for (int j=j0; j<PER; j+=jstep){
    af += FCin[(size_t)j*HDIM + m];
    ah += (float)Hin[(size_t)j*HDIM + m];
  }
  __shared__ float red[256];
  red[threadIdx.x]=af; __syncthreads();
  if (threadIdx.x < 64) atomicAdd(&rootacc[m],    red[m]+red[64+m]+red[128+m]+red[192+m]);
  __syncthreads();
  red[threadIdx.x]=ah; __syncthreads();
  if (threadIdx.x < 64) atomicAdd(&rootacc[64+m], red[m]+red[64+m]+red[128+m]+red[192+m]);
}

__global__ void rootnode_kernel(
    const int* __restrict__ tok, const float* __restrict__ emb,
    const float* __restrict__ Wiou, const float* __restrict__ biou, const float* __restrict__ Uiou,
    const float* __restrict__ rootacc, float* __restrict__ out)
{
  int m = threadIdx.x;
  if (m >= HDIM) return;
  int t = tok[0];
  float ai=biou[m], ao=biou[HDIM+m], au=biou[2*HDIM+m];
  for (int e=0;e<EDIM;e++){
    float xe = emb[(size_t)t*EDIM+e];
    ai += Wiou[(size_t)m*EDIM+e]*xe;
    ao += Wiou[(size_t)(HDIM+m)*EDIM+e]*xe;
    au += Wiou[(size_t)(2*HDIM+m)*EDIM+e]*xe;
  }
  for (int k=0;k<HDIM;k++){
    float hv = rootacc[64+k];
    ai += Uiou[(size_t)m*HDIM+k]*hv;
    ao += Uiou[(size_t)(HDIM+m)*HDIM+k]*hv;
    au += Uiou[(size_t)(2*HDIM+m)*HDIM+k]*hv;
  }
  float c = sigf(ai)*tanh_f(au) + rootacc[m];
  out[m] = sigf(ao)*tanh_f(c);
}

// ================= launch =================
static inline char* alignup(char* p){
  uintptr_t u = (uintptr_t)p;
  u = (u + 255) & ~(uintptr_t)255;
  return (char*)u;
}

extern "C" void kernel_launch(void* const* d_in, const int* in_sizes, int n_in,
                              void* d_out, int out_size, void* d_ws, size_t ws_size,
                              hipStream_t stream)
{
  const int*   tok    = (const int*)d_in[0];
  const int*   parent = (const int*)d_in[1];
  const float* emb    = (const float*)d_in[4];
  const float* Wiou   = (const float*)d_in[5];
  const float* biou   = (const float*)d_in[6];
  const float* Uiou   = (const float*)d_in[7];
  const float* Wf     = (const float*)d_in[8];
  const float* bf     = (const float*)d_in[9];
  const float* Uf     = (const float*)d_in[10];
  float* out = (float*)d_out;

  char* w = (char*)d_ws;
  f16*   HA      = (f16*)w;    w = alignup(w + (size_t)PER*HDIM*sizeof(f16));
  f16*   HB      = (f16*)w;    w = alignup(w + (size_t)PER*HDIM*sizeof(f16));
  float* FCA     = (float*)w;  w = alignup(w + (size_t)PER*HDIM*sizeof(float));
  float* FCB     = (float*)w;  w = alignup(w + (size_t)PER*HDIM*sizeof(float));
  float* Ctmp    = (float*)w;  w = alignup(w + (size_t)PER*HDIM*sizeof(float));
  int*   cnt     = (int*)w;    w = alignup(w + (size_t)NN*sizeof(int));
  int*   off     = (int*)w;    w = alignup(w + (size_t)NN*sizeof(int));
  int*   cursor  = (int*)w;    w = alignup(w + (size_t)NN*sizeof(int));
  int*   childpos= (int*)w;    w = alignup(w + (size_t)NN*sizeof(int));
  int*   ptok    = (int*)w;    w = alignup(w + (size_t)NN*sizeof(int));
  int*   bsum    = (int*)w;    w = alignup(w + 1024*sizeof(int));
  int*   bbase   = (int*)w;    w = alignup(w + 1024*sizeof(int));
  float* embWiou = (float*)w;  w = alignup(w + 1024*NIOU*sizeof(float));
  float* embWf   = (float*)w;  w = alignup(w + 1024*HDIM*sizeof(float));
  float* rootacc = (float*)w;  w = alignup(w + 128*sizeof(float));
  f16*   Ufpack  = (f16*)w;    w = alignup(w + 2*4*64*8*sizeof(f16));
  f16*   Biopack = (f16*)w;    w = alignup(w + 2*12*64*8*sizeof(f16));

  const int gN = (NN + 255)/256;       // 4096

  hipMemsetAsync(cnt, 0, (size_t)NN*sizeof(int), stream);
  hipMemsetAsync(rootacc, 0, 128*sizeof(float), stream);

  count_kernel  <<<gN, 256, 0, stream>>>(parent, cnt);
  scan1_kernel  <<<1024, 256, 0, stream>>>(cnt, bsum);
  scan2_kernel  <<<1, 1024, 0, stream>>>(bsum, bbase);
  scan3_kernel  <<<1024, 256, 0, stream>>>(cnt, bbase, off, cursor);
  scatter_kernel<<<gN, 256, 0, stream>>>(parent, tok, cursor, childpos, ptok);
  table_kernel  <<<1024, 256, 0, stream>>>(emb, Wiou, biou, Wf, bf, embWiou, embWf);
  pack_kernel   <<<1, 256, 0, stream>>>(Uf, Uiou, Ufpack, Biopack);

  // leaf level (children of depth-6 parents): rel positions [0,PER), buffer A
  leafA_kernel<<<(PER*16 + 255)/256, 256, 0, stream>>>(tok, childpos, embWiou, HA, Ctmp);
  leafB_kernel<<<(PER + 255)/256, 256, 0, stream>>>(ptok, embWf, Ufpack, HA, Ctmp, FCA);

  // levels d=6..1: read children buffer (relbase d*PER), write own buffer (outbase (d-1)*PER)
  f16*   Hin = HA;  float* FCin = FCA;
  f16*   Hou = HB;  float* FCou = FCB;
  for (int d=6; d>=1; --d){
    int poff = 1 + (d-1)*PER;
    node_fused<<<(PER + 63)/64, 256, 0, stream>>>(tok, off, childpos, ptok,
                                                  embWiou, embWf, Biopack, Ufpack,
                                                  Hin, FCin, Hou, FCou,
                                                  poff, d*PER, (d-1)*PER);
    f16* th=Hin; Hin=Hou; Hou=th;
    float* tf=FCin; FCin=FCou; FCou=tf;
  }

  // root: children are level-1 nodes at rel positions [0,PER) in the current "in" buffers
  rootred_kernel<<<256, 256, 0, stream>>>(FCin, Hin, rootacc);
  rootnode_kernel<<<1, 64, 0, stream>>>(tok, emb, Wiou, biou, Uiou, rootacc, out);
}

// Round 7
// 791.585 us; speedup vs baseline: 5.2096x; 5.2096x over previous
//
#include <hip/hip_runtime.h>

#define PER  149796
#define NN   1048573          // 1 + 7*PER
#define HDIM 64
#define EDIM 32
#define NIOU 192

typedef _Float16 f16;
typedef _Float16 f16x8 __attribute__((ext_vector_type(8)));
typedef _Float16 f16x4 __attribute__((ext_vector_type(4)));
typedef float    f32x4 __attribute__((ext_vector_type(4)));

__device__ __forceinline__ float sigf(float x){ return 1.0f/(1.0f+__expf(-x)); }
__device__ __forceinline__ float tanh_f(float x){
  float ax = fabsf(x);
  float e  = __expf(-2.0f*ax);
  float t  = (1.0f - e)/(1.0f + e);
  return x < 0.0f ? -t : t;
}

// ================= CSR build (per-level to keep atomic window L2-resident) ==========
// count: children at [lstart, lstart+PER) increment cnt[parent] (600 KB window)
__global__ __launch_bounds__(256) void countL_kernel(const int* __restrict__ parent,
                                                     int* __restrict__ cnt, int lstart){
  int i = blockIdx.x*256 + threadIdx.x;
  if (i >= PER) return;
  atomicAdd(&cnt[parent[lstart + i]], 1);
}

// cnt[0] is never counted (level-1 scatter skipped): scan treats it as PER.
__device__ __forceinline__ int cnt_at(const int* cnt, int idx){
  return (idx == 0) ? PER : cnt[idx];
}

__global__ __launch_bounds__(256) void scan1_kernel(const int* __restrict__ cnt, int* __restrict__ bsum){
  __shared__ int sc[256];
  int b = blockIdx.x, t = threadIdx.x;
  int base = b*1024 + t*4;
  int s = 0;
  #pragma unroll
  for (int e=0;e<4;e++){ int idx=base+e; if (idx<NN) s += cnt_at(cnt, idx); }
  sc[t]=s; __syncthreads();
  for (int d=128; d>0; d>>=1){ if (t<d) sc[t]+=sc[t+d]; __syncthreads(); }
  if (t==0) bsum[b]=sc[0];
}

__global__ __launch_bounds__(1024) void scan2_kernel(const int* __restrict__ bsum, int* __restrict__ bbase){
  __shared__ int sc[1024];
  int t=threadIdx.x;
  sc[t]=bsum[t]; __syncthreads();
  for (int d=1; d<1024; d<<=1){
    int v = (t>=d)? sc[t-d] : 0; __syncthreads();
    sc[t]+=v; __syncthreads();
  }
  bbase[t] = (t==0)?0:sc[t-1];
}

__global__ __launch_bounds__(256) void scan3_kernel(const int* __restrict__ cnt, const int* __restrict__ bbase,
                                                    int* __restrict__ off, int* __restrict__ cursor){
  __shared__ int sc[256];
  int b=blockIdx.x, t=threadIdx.x;
  int base=b*1024+t*4;
  int e0 = (base  <NN)?cnt_at(cnt,base  ):0;
  int e1 = (base+1<NN)?cnt_at(cnt,base+1):0;
  int e2 = (base+2<NN)?cnt_at(cnt,base+2):0;
  int e3 = (base+3<NN)?cnt_at(cnt,base+3):0;
  int tsum=e0+e1+e2+e3;
  sc[t]=tsum; __syncthreads();
  for (int d=1; d<256; d<<=1){
    int v=(t>=d)?sc[t-d]:0; __syncthreads();
    sc[t]+=v; __syncthreads();
  }
  int x = bbase[b] + ((t==0)?0:sc[t-1]);
  if (base  <NN){ off[base  ]=x;          cursor[base  ]=x; }
  if (base+1<NN){ off[base+1]=x+e0;       cursor[base+1]=x+e0; }
  if (base+2<NN){ off[base+2]=x+e0+e1;    cursor[base+2]=x+e0+e1; }
  if (base+3<NN){ off[base+3]=x+e0+e1+e2; cursor[base+3]=x+e0+e1+e2; }
}

// scatter: children at [lstart, lstart+PER); cursor window = parents' 600 KB range
__global__ __launch_bounds__(256) void scatterL_kernel(const int* __restrict__ parent,
    const int* __restrict__ tok, int* __restrict__ cursor,
    int* __restrict__ childpos, int* __restrict__ ptok, int lstart){
  int i = blockIdx.x*256 + threadIdx.x;
  if (i >= PER) return;
  int g = lstart + i;
  int jp = parent[g];
  int pos = atomicAdd(&cursor[jp], 1);
  childpos[g] = pos;
  ptok[pos] = tok[jp];
}

// ================= weight tables / MFMA packs =================
__global__ __launch_bounds__(256) void table_kernel(
    const float* __restrict__ emb, const float* __restrict__ Wiou, const float* __restrict__ biou,
    const float* __restrict__ Wf, const float* __restrict__ bf,
    float* __restrict__ embWiou, float* __restrict__ embWf)
{
  int v = blockIdx.x;
  int m = threadIdx.x;
  const float* x = emb + (size_t)v*EDIM;
  if (m < NIOU){
    float a = biou[m];
    #pragma unroll
    for (int e=0;e<EDIM;e++) a += Wiou[m*EDIM+e]*x[e];
    embWiou[(size_t)v*NIOU + m] = a;
  } else {
    int mm = m - NIOU;
    float a = bf[mm];
    #pragma unroll
    for (int e=0;e<EDIM;e++) a += Wf[mm*EDIM+e]*x[e];
    embWf[(size_t)v*HDIM + mm] = a;
  }
}

// B-frag order for mfma_f32_16x16x32_f16 (verified R4): lane L: n=t*16+(L&15), k=s*32+(L>>4)*8+j
__global__ void pack_kernel(const float* __restrict__ Uf, const float* __restrict__ Uiou,
                            f16* __restrict__ Bf, f16* __restrict__ Biou)
{
  for (int i = threadIdx.x; i < 2*4*64*8; i += 256){
    int j = i & 7, L = (i>>3)&63, st = i>>9;
    int t = st & 3, s = st >> 2;
    int k = s*32 + (L>>4)*8 + j;
    int n = t*16 + (L&15);
    Bf[i] = (f16)Uf[n*HDIM + k];
  }
  for (int i = threadIdx.x; i < 2*12*64*8; i += 256){
    int j = i & 7, L = (i>>3)&63, st = i>>9;
    int t = st % 12, s = st / 12;
    int k = s*32 + (L>>4)*8 + j;
    int n = t*16 + (L&15);
    Biou[i] = (f16)Uiou[n*HDIM + k];
  }
}

// ================= leaves =================
__global__ __launch_bounds__(256) void leafA_kernel(
    const int* __restrict__ tok, const int* __restrict__ childpos,
    const float* __restrict__ embWiou, f16* __restrict__ Hout, float* __restrict__ Ctmp)
{
  int gid = blockIdx.x*256 + threadIdx.x;
  if (gid >= PER*16) return;
  int j = gid >> 4, sub = gid & 15;
  int g = 1 + 6*PER + j;
  int t = tok[g];
  const float* row = embWiou + (size_t)t*NIOU;
  float4 i4 = *(const float4*)(row + sub*4);
  float4 o4 = *(const float4*)(row + 64 + sub*4);
  float4 u4 = *(const float4*)(row + 128 + sub*4);
  float4 cv; f16x4 hv;
  cv.x = sigf(i4.x)*tanh_f(u4.x); hv.x = (f16)(sigf(o4.x)*tanh_f(cv.x));
  cv.y = sigf(i4.y)*tanh_f(u4.y); hv.y = (f16)(sigf(o4.y)*tanh_f(cv.y));
  cv.z = sigf(i4.z)*tanh_f(u4.z); hv.z = (f16)(sigf(o4.z)*tanh_f(cv.z));
  cv.w = sigf(i4.w)*tanh_f(u4.w); hv.w = (f16)(sigf(o4.w)*tanh_f(cv.w));
  int pos = childpos[g] - 6*PER;          // relative leaf position in [0, PER)
  *(float4*)(Ctmp + (size_t)pos*HDIM + sub*4) = cv;
  *(f16x4*)(Hout + (size_t)pos*HDIM + sub*4) = hv;
}

__global__ __launch_bounds__(256) void leafB_kernel(
    const int* __restrict__ ptok, const float* __restrict__ embWf, const f16* __restrict__ Ufpack,
    const f16* __restrict__ Hin, const float* __restrict__ Ctmp, float* __restrict__ FCout)
{
  int lane = threadIdx.x & 63;
  int wv   = threadIdx.x >> 6;
  int base = (blockIdx.x*4 + wv)*64;
  if (base >= PER) return;
  int q = lane >> 4, c16 = lane & 15;
  const f16x8* Bp = (const f16x8*)Ufpack;
  f16x8 B[2][4];
  #pragma unroll
  for (int s=0;s<2;s++)
    #pragma unroll
    for (int t=0;t<4;t++) B[s][t] = Bp[(s*4+t)*64 + lane];
  f32x4 acc[4][4];
  #pragma unroll
  for (int a=0;a<4;a++)
    #pragma unroll
    for (int b=0;b<4;b++) acc[a][b] = (f32x4){0.f,0.f,0.f,0.f};
  #pragma unroll
  for (int tm=0;tm<4;tm++){
    int r0 = base + tm*16 + c16;
    if (r0 > PER-1) r0 = PER-1;
    const f16* hp = Hin + (size_t)r0*HDIM;
    f16x8 A0 = *(const f16x8*)(hp + q*8);
    f16x8 A1 = *(const f16x8*)(hp + 32 + q*8);
    #pragma unroll
    for (int nt=0;nt<4;nt++){
      acc[tm][nt] = __builtin_amdgcn_mfma_f32_16x16x32_f16(A0, B[0][nt], acc[tm][nt], 0,0,0);
      acc[tm][nt] = __builtin_amdgcn_mfma_f32_16x16x32_f16(A1, B[1][nt], acc[tm][nt], 0,0,0);
    }
  }
  #pragma unroll
  for (int tm=0;tm<4;tm++){
    #pragma unroll
    for (int r=0;r<4;r++){
      int lrow = base + tm*16 + q*4 + r;
      bool ok = lrow < PER;
      int rl = ok ? lrow : PER-1;
      int wt = ptok[6*PER + rl];
      const float* wr = embWf + (size_t)wt*HDIM;
      #pragma unroll
      for (int nt=0;nt<4;nt++){
        int col = nt*16 + c16;
        float gg = acc[tm][nt][r] + wr[col];
        float v = sigf(gg) * Ctmp[(size_t)rl*HDIM + col];
        if (ok) FCout[(size_t)rl*HDIM + col] = v;
      }
    }
  }
}

// ================= fused node kernel =================
__global__ __launch_bounds__(256) void node_fused(
    const int* __restrict__ tok, const int* __restrict__ off,
    const int* __restrict__ childpos, const int* __restrict__ ptok,
    const float* __restrict__ embWiou, const float* __restrict__ embWf,
    const f16* __restrict__ Biopack, const f16* __restrict__ Ufpack,
    const f16* __restrict__ Hin, const float* __restrict__ FCin,
    f16* __restrict__ Hout, float* __restrict__ FCout,
    int poff, int relbase, int outbase, int identityOut)
{
  __shared__ f16   Ah[64*72];
  __shared__ float FAs[64*68];
  int lane = threadIdx.x & 63;
  int wv   = __builtin_amdgcn_readfirstlane(threadIdx.x >> 6);
  int p0   = wv*16;
  int j0   = blockIdx.x*64 + p0;
  // ---- phase 1: segmented stream-sum over rel child rows
  int pCur = off[poff + ((j0 < PER) ? j0 : (PER-1))] - relbase;
  #pragma unroll 1
  for (int i=0;i<16;i++){
    int j = j0 + i;
    float hs = 0.f, fa = 0.f;
    if (j < PER){
      int pEnd = off[poff + j + 1] - relbase;
      for (int p=pCur; p<pEnd; ++p){
        hs += (float)Hin[(size_t)p*HDIM + lane];
        fa += FCin[(size_t)p*HDIM + lane];
      }
      pCur = pEnd;
    }
    Ah[(p0+i)*72 + lane] = (f16)hs;
    FAs[(p0+i)*68 + lane] = fa;
  }
  __syncthreads();
  // ---- phase 2: iou MFMA + epilogue
  int q = lane>>4, c16 = lane&15;
  f16x8 A0 = *(const f16x8*)(Ah + (p0+c16)*72 + q*8);
  f16x8 A1 = *(const f16x8*)(Ah + (p0+c16)*72 + 32 + q*8);
  const f16x8* Bp = (const f16x8*)Biopack;
  f32x4 acc[12];
  #pragma unroll
  for (int nt=0;nt<12;nt++) acc[nt] = (f32x4){0.f,0.f,0.f,0.f};
  #pragma unroll
  for (int nt=0;nt<12;nt++){
    f16x8 B0 = Bp[nt*64 + lane];
    f16x8 B1 = Bp[(12+nt)*64 + lane];
    acc[nt] = __builtin_amdgcn_mfma_f32_16x16x32_f16(A0, B0, acc[nt], 0,0,0);
    acc[nt] = __builtin_amdgcn_mfma_f32_16x16x32_f16(A1, B1, acc[nt], 0,0,0);
  }
  int tok0 = identityOut ? tok[0] : 0;
  float cc[4][4];
  f16   hh[4][4];
  int   opos_[4]; int wt_[4]; bool ok_[4];
  #pragma unroll
  for (int r=0;r<4;r++){
    int j = j0 + q*4 + r;
    bool ok = j < PER;
    int jl = ok ? j : PER-1;
    int g = poff + jl;
    int tk = tok[g];
    const float* tr = embWiou + (size_t)tk*NIOU;
    int opg = identityOut ? (outbase + jl) : childpos[g];
    int op  = opg - outbase;
    opos_[r]=op; ok_[r]=ok;
    wt_[r] = identityOut ? tok0 : ptok[opg];
    int prow = p0 + q*4 + r;
    #pragma unroll
    for (int nt=0;nt<4;nt++){
      int col = nt*16 + c16;
      float ai = acc[nt][r]   + tr[col];
      float ao = acc[nt+4][r] + tr[64+col];
      float au = acc[nt+8][r] + tr[128+col];
      float fa = FAs[prow*68 + col];
      float c = sigf(ai)*tanh_f(au) + fa;
      float h = sigf(ao)*tanh_f(c);
      cc[r][nt] = c;
      hh[r][nt] = (f16)h;
      if (ok) Hout[(size_t)op*HDIM + col] = (f16)h;
    }
  }
  __syncthreads();                 // all phase-2 LDS reads done
  // ---- phase 3: h -> Ah, Uf MFMA, FC
  #pragma unroll
  for (int r=0;r<4;r++)
    #pragma unroll
    for (int nt=0;nt<4;nt++)
      Ah[(p0+q*4+r)*72 + nt*16 + c16] = hh[r][nt];
  __syncthreads();
  f16x8 H0 = *(const f16x8*)(Ah + (p0+c16)*72 + q*8);
  f16x8 H1 = *(const f16x8*)(Ah + (p0+c16)*72 + 32 + q*8);
  const f16x8* Up = (const f16x8*)Ufpack;
  f32x4 g4[4];
  #pragma unroll
  for (int nt=0;nt<4;nt++) g4[nt] = (f32x4){0.f,0.f,0.f,0.f};
  #pragma unroll
  for (int nt=0;nt<4;nt++){
    f16x8 B0 = Up[nt*64 + lane];
    f16x8 B1 = Up[(4+nt)*64 + lane];
    g4[nt] = __builtin_amdgcn_mfma_f32_16x16x32_f16(H0, B0, g4[nt], 0,0,0);
    g4[nt] = __builtin_amdgcn_mfma_f32_16x16x32_f16(H1, B1, g4[nt], 0,0,0);
  }
  #pragma unroll
  for (int r=0;r<4;r++){
    if (!ok_[r]) continue;
    const float* wr = embWf + (size_t)wt_[r]*HDIM;
    int op = opos_[r];
    #pragma unroll
    for (int nt=0;nt<4;nt++){
      int col = nt*16 + c16;
      float v = sigf(g4[nt][r] + wr[col]) * cc[r][nt];
      FCout[(size_t)op*HDIM + col] = v;
    }
  }
}

// ================= root =================
__global__ __launch_bounds__(256) void rootred_kernel(
    const float* __restrict__ FCin, const f16* __restrict__ Hin, float* __restrict__ rootacc)
{
  int t = blockIdx.x*blockDim.x + threadIdx.x;
  int m = t & 63;
  int j0 = t >> 6;
  int jstep = (gridDim.x*blockDim.x) >> 6;
  float af=0.f, ah=0.f;
  for (int j=j0; j<PER; j+=jstep){
    af += FCin[(size_t)j*HDIM + m];
    ah += (float)Hin[(size_t)j*HDIM + m];
  }
  __shared__ float red[256];
  red[threadIdx.x]=af; __syncthreads();
  if (threadIdx.x < 64) atomicAdd(&rootacc[m],    red[m]+red[64+m]+red[128+m]+red[192+m]);
  __syncthreads();
  red[threadIdx.x]=ah; __syncthreads();
  if (threadIdx.x < 64) atomicAdd(&rootacc[64+m], red[m]+red[64+m]+red[128+m]+red[192+m]);
}

__global__ void rootnode_kernel(
    const int* __restrict__ tok, const float* __restrict__ emb,
    const float* __restrict__ Wiou, const float* __restrict__ biou, const float* __restrict__ Uiou,
    const float* __restrict__ rootacc, float* __restrict__ out)
{
  int m = threadIdx.x;
  if (m >= HDIM) return;
  int t = tok[0];
  float ai=biou[m], ao=biou[HDIM+m], au=biou[2*HDIM+m];
  for (int e=0;e<EDIM;e++){
    float xe = emb[(size_t)t*EDIM+e];
    ai += Wiou[(size_t)m*EDIM+e]*xe;
    ao += Wiou[(size_t)(HDIM+m)*EDIM+e]*xe;
    au += Wiou[(size_t)(2*HDIM+m)*EDIM+e]*xe;
  }
  for (int k=0;k<HDIM;k++){
    float hv = rootacc[64+k];
    ai += Uiou[(size_t)m*HDIM+k]*hv;
    ao += Uiou[(size_t)(HDIM+m)*HDIM+k]*hv;
    au += Uiou[(size_t)(2*HDIM+m)*HDIM+k]*hv;
  }
  float c = sigf(ai)*tanh_f(au) + rootacc[m];
  out[m] = sigf(ao)*tanh_f(c);
}

// ================= launch =================
static inline char* alignup(char* p){
  uintptr_t u = (uintptr_t)p;
  u = (u + 255) & ~(uintptr_t)255;
  return (char*)u;
}

extern "C" void kernel_launch(void* const* d_in, const int* in_sizes, int n_in,
                              void* d_out, int out_size, void* d_ws, size_t ws_size,
                              hipStream_t stream)
{
  const int*   tok    = (const int*)d_in[0];
  const int*   parent = (const int*)d_in[1];
  const float* emb    = (const float*)d_in[4];
  const float* Wiou   = (const float*)d_in[5];
  const float* biou   = (const float*)d_in[6];
  const float* Uiou   = (const float*)d_in[7];
  const float* Wf     = (const float*)d_in[8];
  const float* bf     = (const float*)d_in[9];
  const float* Uf     = (const float*)d_in[10];
  float* out = (float*)d_out;

  char* w = (char*)d_ws;
  f16*   HA      = (f16*)w;    w = alignup(w + (size_t)PER*HDIM*sizeof(f16));
  f16*   HB      = (f16*)w;    w = alignup(w + (size_t)PER*HDIM*sizeof(f16));
  float* FCA     = (float*)w;  w = alignup(w + (size_t)PER*HDIM*sizeof(float));
  float* FCB     = (float*)w;  w = alignup(w + (size_t)PER*HDIM*sizeof(float));
  float* Ctmp    = (float*)w;  w = alignup(w + (size_t)PER*HDIM*sizeof(float));
  int*   cnt     = (int*)w;    w = alignup(w + (size_t)NN*sizeof(int));
  int*   off     = (int*)w;    w = alignup(w + (size_t)NN*sizeof(int));
  int*   cursor  = (int*)w;    w = alignup(w + (size_t)NN*sizeof(int));
  int*   childpos= (int*)w;    w = alignup(w + (size_t)NN*sizeof(int));
  int*   ptok    = (int*)w;    w = alignup(w + (size_t)NN*sizeof(int));
  int*   bsum    = (int*)w;    w = alignup(w + 1024*sizeof(int));
  int*   bbase   = (int*)w;    w = alignup(w + 1024*sizeof(int));
  float* embWiou = (float*)w;  w = alignup(w + 1024*NIOU*sizeof(float));
  float* embWf   = (float*)w;  w = alignup(w + 1024*HDIM*sizeof(float));
  float* rootacc = (float*)w;  w = alignup(w + 128*sizeof(float));
  f16*   Ufpack  = (f16*)w;    w = alignup(w + 2*4*64*8*sizeof(f16));
  f16*   Biopack = (f16*)w;    w = alignup(w + 2*12*64*8*sizeof(f16));

  const int gPER = (PER + 255)/256;    // 586

  hipMemsetAsync(cnt, 0, (size_t)NN*sizeof(int), stream);
  hipMemsetAsync(rootacc, 0, 128*sizeof(float), stream);

  // per-level counts (levels 2..7 children; level-1 handled as cnt[0]=PER inside scan)
  for (int l=2; l<=7; ++l)
    countL_kernel<<<gPER, 256, 0, stream>>>(parent, cnt, 1 + (l-1)*PER);
  scan1_kernel  <<<1024, 256, 0, stream>>>(cnt, bsum);
  scan2_kernel  <<<1, 1024, 0, stream>>>(bsum, bbase);
  scan3_kernel  <<<1024, 256, 0, stream>>>(cnt, bbase, off, cursor);
  // per-level scatters (levels 2..7); level-1 uses identity mapping in node_fused
  for (int l=2; l<=7; ++l)
    scatterL_kernel<<<gPER, 256, 0, stream>>>(parent, tok, cursor, childpos, ptok, 1 + (l-1)*PER);

  table_kernel<<<1024, 256, 0, stream>>>(emb, Wiou, biou, Wf, bf, embWiou, embWf);
  pack_kernel <<<1, 256, 0, stream>>>(Uf, Uiou, Ufpack, Biopack);

  // leaf level (children of depth-6 parents): rel positions [0,PER), buffer A
  leafA_kernel<<<(PER*16 + 255)/256, 256, 0, stream>>>(tok, childpos, embWiou, HA, Ctmp);
  leafB_kernel<<<gPER, 256, 0, stream>>>(ptok, embWf, Ufpack, HA, Ctmp, FCA);

  // levels d=6..1: read children buffer (relbase d*PER), write own buffer (outbase (d-1)*PER)
  f16*   Hin = HA;  float* FCin = FCA;
  f16*   Hou = HB;  float* FCou = FCB;
  for (int d=6; d>=1; --d){
    int poff = 1 + (d-1)*PER;
    node_fused<<<(PER + 63)/64, 256, 0, stream>>>(tok, off, childpos, ptok,
                                                  embWiou, embWf, Biopack, Ufpack,
                                                  Hin, FCin, Hou, FCou,
                                                  poff, d*PER, (d-1)*PER, (d==1) ? 1 : 0);
    f16* th=Hin; Hin=Hou; Hou=th;
    float* tf=FCin; FCin=FCou; FCou=tf;
  }

  // root: children are level-1 nodes at rel positions [0,PER)
  rootred_kernel<<<256, 256, 0, stream>>>(FCin, Hin, rootacc);
  rootnode_kernel<<<1, 64, 0, stream>>>(tok, emb, Wiou, biou, Uiou, rootacc, out);
}

// Round 8
// 592.492 us; speedup vs baseline: 6.9602x; 1.3360x over previous
//
#include <hip/hip_runtime.h>

#define PER  149796
#define NN   1048573          // 1 + 7*PER
#define HDIM 64
#define EDIM 32
#define NIOU 192
#define STG  96               // staged child rows per chunk

typedef _Float16 f16;
typedef _Float16 f16x8 __attribute__((ext_vector_type(8)));
typedef _Float16 f16x4 __attribute__((ext_vector_type(4)));
typedef _Float16 f16x2 __attribute__((ext_vector_type(2)));
typedef float    f32x4 __attribute__((ext_vector_type(4)));

typedef __attribute__((address_space(1))) const unsigned gu32;
typedef __attribute__((address_space(3))) unsigned lu32;

__device__ __forceinline__ float sigf(float x){ return 1.0f/(1.0f+__expf(-x)); }
__device__ __forceinline__ float tanh_f(float x){
  float ax = fabsf(x);
  float e  = __expf(-2.0f*ax);
  float t  = (1.0f - e)/(1.0f + e);
  return x < 0.0f ? -t : t;
}

// ================= CSR build =================
// all levels 2..7 children in one launch; per-block atomic window stays ~600KB (per level)
__global__ __launch_bounds__(256) void countAll_kernel(const int* __restrict__ parent,
                                                       int* __restrict__ cnt){
  int idx = blockIdx.x*256 + threadIdx.x;
  if (idx >= 6*PER) return;
  atomicAdd(&cnt[parent[1 + PER + idx]], 1);
}

// cnt[0] never counted (level-1 scatter skipped): treat as PER in scans.
__device__ __forceinline__ int cnt_at(const int* cnt, int idx){
  return (idx == 0) ? PER : cnt[idx];
}

__global__ __launch_bounds__(256) void scan1_kernel(const int* __restrict__ cnt, int* __restrict__ bsum){
  __shared__ int sc[256];
  int b = blockIdx.x, t = threadIdx.x;
  int base = b*1024 + t*4;
  int s = 0;
  #pragma unroll
  for (int e=0;e<4;e++){ int idx=base+e; if (idx<NN) s += cnt_at(cnt, idx); }
  sc[t]=s; __syncthreads();
  for (int d=128; d>0; d>>=1){ if (t<d) sc[t]+=sc[t+d]; __syncthreads(); }
  if (t==0) bsum[b]=sc[0];
}

__global__ __launch_bounds__(1024) void scan2_kernel(const int* __restrict__ bsum, int* __restrict__ bbase){
  __shared__ int sc[1024];
  int t=threadIdx.x;
  sc[t]=bsum[t]; __syncthreads();
  for (int d=1; d<1024; d<<=1){
    int v = (t>=d)? sc[t-d] : 0; __syncthreads();
    sc[t]+=v; __syncthreads();
  }
  bbase[t] = (t==0)?0:sc[t-1];
}

__global__ __launch_bounds__(256) void scan3_kernel(const int* __restrict__ cnt, const int* __restrict__ bbase,
                                                    int* __restrict__ off, int* __restrict__ cursor){
  __shared__ int sc[256];
  int b=blockIdx.x, t=threadIdx.x;
  int base=b*1024+t*4;
  int e0 = (base  <NN)?cnt_at(cnt,base  ):0;
  int e1 = (base+1<NN)?cnt_at(cnt,base+1):0;
  int e2 = (base+2<NN)?cnt_at(cnt,base+2):0;
  int e3 = (base+3<NN)?cnt_at(cnt,base+3):0;
  int tsum=e0+e1+e2+e3;
  sc[t]=tsum; __syncthreads();
  for (int d=1; d<256; d<<=1){
    int v=(t>=d)?sc[t-d]:0; __syncthreads();
    sc[t]+=v; __syncthreads();
  }
  int x = bbase[b] + ((t==0)?0:sc[t-1]);
  if (base  <NN){ off[base  ]=x;          cursor[base  ]=x; }
  if (base+1<NN){ off[base+1]=x+e0;       cursor[base+1]=x+e0; }
  if (base+2<NN){ off[base+2]=x+e0+e1;    cursor[base+2]=x+e0+e1; }
  if (base+3<NN){ off[base+3]=x+e0+e1+e2; cursor[base+3]=x+e0+e1+e2; }
}

__global__ __launch_bounds__(256) void scatterAll_kernel(const int* __restrict__ parent,
    const int* __restrict__ tok, int* __restrict__ cursor,
    int* __restrict__ childpos, int* __restrict__ ptok){
  int idx = blockIdx.x*256 + threadIdx.x;
  if (idx >= 6*PER) return;
  int g = 1 + PER + idx;
  int jp = parent[g];
  int pos = atomicAdd(&cursor[jp], 1);
  childpos[g] = pos;
  ptok[pos] = tok[jp];
}

// ================= tables + MFMA packs (fused) =================
// B-frag order for mfma_f32_16x16x32_f16 (verified R4): lane L: n=t*16+(L&15), k=s*32+(L>>4)*8+j
__global__ __launch_bounds__(256) void tablepack_kernel(
    const float* __restrict__ emb, const float* __restrict__ Wiou, const float* __restrict__ biou,
    const float* __restrict__ Wf, const float* __restrict__ bf,
    const float* __restrict__ Uf, const float* __restrict__ Uiou,
    float* __restrict__ embWiou, float* __restrict__ embWf,
    f16* __restrict__ Bfp, f16* __restrict__ Biop)
{
  if (blockIdx.x < 1024){
    int v = blockIdx.x;
    int m = threadIdx.x;
    const float* x = emb + (size_t)v*EDIM;
    if (m < NIOU){
      float a = biou[m];
      #pragma unroll
      for (int e=0;e<EDIM;e++) a += Wiou[m*EDIM+e]*x[e];
      embWiou[(size_t)v*NIOU + m] = a;
    } else {
      int mm = m - NIOU;
      float a = bf[mm];
      #pragma unroll
      for (int e=0;e<EDIM;e++) a += Wf[mm*EDIM+e]*x[e];
      embWf[(size_t)v*HDIM + mm] = a;
    }
  } else {
    for (int i = threadIdx.x; i < 2*4*64*8; i += 256){
      int j = i & 7, L = (i>>3)&63, st = i>>9;
      int t = st & 3, s = st >> 2;
      int k = s*32 + (L>>4)*8 + j;
      int n = t*16 + (L&15);
      Bfp[i] = (f16)Uf[n*HDIM + k];
    }
    for (int i = threadIdx.x; i < 2*12*64*8; i += 256){
      int j = i & 7, L = (i>>3)&63, st = i>>9;
      int t = st % 12, s = st / 12;
      int k = s*32 + (L>>4)*8 + j;
      int n = t*16 + (L&15);
      Biop[i] = (f16)Uiou[n*HDIM + k];
    }
  }
}

// ================= leaves =================
// leafA: h,c from table; h -> Htmp (plain f16, sorted) + HF.x; c -> Ctmp
__global__ __launch_bounds__(256) void leafA_kernel(
    const int* __restrict__ tok, const int* __restrict__ childpos,
    const float* __restrict__ embWiou, f16* __restrict__ Htmp,
    f16x2* __restrict__ HF, float* __restrict__ Ctmp)
{
  int gid = blockIdx.x*256 + threadIdx.x;
  if (gid >= PER*16) return;
  int j = gid >> 4, sub = gid & 15;
  int g = 1 + 6*PER + j;
  int t = tok[g];
  const float* row = embWiou + (size_t)t*NIOU;
  float4 i4 = *(const float4*)(row + sub*4);
  float4 o4 = *(const float4*)(row + 64 + sub*4);
  float4 u4 = *(const float4*)(row + 128 + sub*4);
  float4 cv; f16x4 hv;
  cv.x = sigf(i4.x)*tanh_f(u4.x); hv.x = (f16)(sigf(o4.x)*tanh_f(cv.x));
  cv.y = sigf(i4.y)*tanh_f(u4.y); hv.y = (f16)(sigf(o4.y)*tanh_f(cv.y));
  cv.z = sigf(i4.z)*tanh_f(u4.z); hv.z = (f16)(sigf(o4.z)*tanh_f(cv.z));
  cv.w = sigf(i4.w)*tanh_f(u4.w); hv.w = (f16)(sigf(o4.w)*tanh_f(cv.w));
  int pos = childpos[g] - 6*PER;          // relative leaf position in [0, PER)
  *(float4*)(Ctmp + (size_t)pos*HDIM + sub*4) = cv;
  *(f16x4*)(Htmp + (size_t)pos*HDIM + sub*4) = hv;
  f16x2* hf = HF + (size_t)pos*HDIM + sub*4;
  hf[0].x = hv.x; hf[1].x = hv.y; hf[2].x = hv.z; hf[3].x = hv.w;
}

// leafB: FC for leaf level, streaming rel rows [0,PER); writes HF.y
__global__ __launch_bounds__(256) void leafB_kernel(
    const int* __restrict__ ptok, const float* __restrict__ embWf, const f16* __restrict__ Ufpack,
    const f16* __restrict__ Htmp, const float* __restrict__ Ctmp, f16x2* __restrict__ HF)
{
  int lane = threadIdx.x & 63;
  int wv   = threadIdx.x >> 6;
  int base = (blockIdx.x*4 + wv)*64;
  if (base >= PER) return;
  int q = lane >> 4, c16 = lane & 15;
  const f16x8* Bp = (const f16x8*)Ufpack;
  f16x8 B[2][4];
  #pragma unroll
  for (int s=0;s<2;s++)
    #pragma unroll
    for (int t=0;t<4;t++) B[s][t] = Bp[(s*4+t)*64 + lane];
  f32x4 acc[4][4];
  #pragma unroll
  for (int a=0;a<4;a++)
    #pragma unroll
    for (int b=0;b<4;b++) acc[a][b] = (f32x4){0.f,0.f,0.f,0.f};
  #pragma unroll
  for (int tm=0;tm<4;tm++){
    int r0 = base + tm*16 + c16;
    if (r0 > PER-1) r0 = PER-1;
    const f16* hp = Htmp + (size_t)r0*HDIM;
    f16x8 A0 = *(const f16x8*)(hp + q*8);
    f16x8 A1 = *(const f16x8*)(hp + 32 + q*8);
    #pragma unroll
    for (int nt=0;nt<4;nt++){
      acc[tm][nt] = __builtin_amdgcn_mfma_f32_16x16x32_f16(A0, B[0][nt], acc[tm][nt], 0,0,0);
      acc[tm][nt] = __builtin_amdgcn_mfma_f32_16x16x32_f16(A1, B[1][nt], acc[tm][nt], 0,0,0);
    }
  }
  #pragma unroll
  for (int tm=0;tm<4;tm++){
    #pragma unroll
    for (int r=0;r<4;r++){
      int lrow = base + tm*16 + q*4 + r;
      bool ok = lrow < PER;
      int rl = ok ? lrow : PER-1;
      int wt = ptok[6*PER + rl];
      const float* wr = embWf + (size_t)wt*HDIM;
      #pragma unroll
      for (int nt=0;nt<4;nt++){
        int col = nt*16 + c16;
        float gg = acc[tm][nt][r] + wr[col];
        float v = sigf(gg) * Ctmp[(size_t)rl*HDIM + col];
        if (ok) HF[(size_t)rl*HDIM + col].y = (f16)v;
      }
    }
  }
}

// ================= fused node kernel =================
// phase1: async-stage contiguous child rows into LDS, segmented sum from LDS
// phase2: MFMA Hsum @ Uiou^T + activation epilogue (h,c in regs)
// phase3: h -> LDS -> A-frags -> MFMA Uf -> write {h,fc} f16x2
__global__ __launch_bounds__(256) void node_fused(
    const int* __restrict__ tok, const int* __restrict__ off,
    const int* __restrict__ childpos, const int* __restrict__ ptok,
    const float* __restrict__ embWiou, const float* __restrict__ embWf,
    const f16* __restrict__ Biopack, const f16* __restrict__ Ufpack,
    const f16x2* __restrict__ HFin, f16x2* __restrict__ HFout,
    int poff, int relbase, int outbase, int identityOut)
{
  __shared__ f16x2 stage[STG*64];    // 24.0 KB
  __shared__ f16   Ah[64*72];        //  9.2 KB
  __shared__ float FAs[64*68];       // 17.4 KB
  int lane = threadIdx.x & 63;
  int wv   = __builtin_amdgcn_readfirstlane(threadIdx.x >> 6);
  int p0   = wv*16;
  int j0b  = blockIdx.x*64;
  int j0   = j0b + p0;
  // block child range (contiguous, CSR-sorted)
  int ei = j0b + 64; if (ei > PER) ei = PER;
  int S = off[poff + j0b] - relbase;
  int E = off[poff + ei]  - relbase;
  // per-parent segment bounds (clamped indices give empty segments for tail)
  int sB[17];
  #pragma unroll
  for (int i=0;i<=16;i++){
    int jj = j0 + i; if (jj > PER) jj = PER;
    sB[i] = off[poff + jj] - relbase;
  }
  float hs[16], fa[16];
  #pragma unroll
  for (int i=0;i<16;i++){ hs[i]=0.f; fa[i]=0.f; }
  const unsigned* HFinU = (const unsigned*)HFin;
  for (int cb = S; cb < E; cb += STG){
    int n = E - cb; if (n > STG) n = STG;
    for (int r = wv; r < n; r += 4){
      gu32* gp = (gu32*)(HFinU + (size_t)(cb+r)*HDIM) + lane;
      __builtin_amdgcn_global_load_lds(gp, (lu32*)&stage[r*HDIM], 4, 0, 0);
    }
    __syncthreads();
    int lim = cb + n;
    #pragma unroll
    for (int i=0;i<16;i++){
      int lo = sB[i]   > cb  ? sB[i]   : cb;
      int hi = sB[i+1] < lim ? sB[i+1] : lim;
      for (int p=lo; p<hi; ++p){
        f16x2 v = stage[(p-cb)*HDIM + lane];
        hs[i] += (float)v.x; fa[i] += (float)v.y;
      }
    }
    __syncthreads();
  }
  #pragma unroll
  for (int i=0;i<16;i++){
    Ah[(p0+i)*72 + lane]  = (f16)hs[i];
    FAs[(p0+i)*68 + lane] = fa[i];
  }
  __syncthreads();
  // ---- phase 2: iou MFMA + epilogue
  int q = lane>>4, c16 = lane&15;
  f16x8 A0 = *(const f16x8*)(Ah + (p0+c16)*72 + q*8);
  f16x8 A1 = *(const f16x8*)(Ah + (p0+c16)*72 + 32 + q*8);
  const f16x8* Bp = (const f16x8*)Biopack;
  f32x4 acc[12];
  #pragma unroll
  for (int nt=0;nt<12;nt++) acc[nt] = (f32x4){0.f,0.f,0.f,0.f};
  #pragma unroll
  for (int nt=0;nt<12;nt++){
    f16x8 B0 = Bp[nt*64 + lane];
    f16x8 B1 = Bp[(12+nt)*64 + lane];
    acc[nt] = __builtin_amdgcn_mfma_f32_16x16x32_f16(A0, B0, acc[nt], 0,0,0);
    acc[nt] = __builtin_amdgcn_mfma_f32_16x16x32_f16(A1, B1, acc[nt], 0,0,0);
  }
  int tok0 = identityOut ? tok[0] : 0;
  float cc[4][4];
  f16   hh[4][4];
  int   opos_[4]; int wt_[4]; bool ok_[4];
  #pragma unroll
  for (int r=0;r<4;r++){
    int j = j0 + q*4 + r;
    bool ok = j < PER;
    int jl = ok ? j : PER-1;
    int g = poff + jl;
    int tk = tok[g];
    const float* tr = embWiou + (size_t)tk*NIOU;
    int opg = identityOut ? (outbase + jl) : childpos[g];
    int op  = opg - outbase;
    opos_[r]=op; ok_[r]=ok;
    wt_[r] = identityOut ? tok0 : ptok[opg];
    int prow = p0 + q*4 + r;
    #pragma unroll
    for (int nt=0;nt<4;nt++){
      int col = nt*16 + c16;
      float ai = acc[nt][r]   + tr[col];
      float ao = acc[nt+4][r] + tr[64+col];
      float au = acc[nt+8][r] + tr[128+col];
      float fav = FAs[prow*68 + col];
      float c = sigf(ai)*tanh_f(au) + fav;
      float h = sigf(ao)*tanh_f(c);
      cc[r][nt] = c;
      hh[r][nt] = (f16)h;
    }
  }
  __syncthreads();
  // ---- phase 3: h -> Ah, Uf MFMA, write {h,fc}
  #pragma unroll
  for (int r=0;r<4;r++)
    #pragma unroll
    for (int nt=0;nt<4;nt++)
      Ah[(p0+q*4+r)*72 + nt*16 + c16] = hh[r][nt];
  __syncthreads();
  f16x8 H0 = *(const f16x8*)(Ah + (p0+c16)*72 + q*8);
  f16x8 H1 = *(const f16x8*)(Ah + (p0+c16)*72 + 32 + q*8);
  const f16x8* Up = (const f16x8*)Ufpack;
  f32x4 g4[4];
  #pragma unroll
  for (int nt=0;nt<4;nt++) g4[nt] = (f32x4){0.f,0.f,0.f,0.f};
  #pragma unroll
  for (int nt=0;nt<4;nt++){
    f16x8 B0 = Up[nt*64 + lane];
    f16x8 B1 = Up[(4+nt)*64 + lane];
    g4[nt] = __builtin_amdgcn_mfma_f32_16x16x32_f16(H0, B0, g4[nt], 0,0,0);
    g4[nt] = __builtin_amdgcn_mfma_f32_16x16x32_f16(H1, B1, g4[nt], 0,0,0);
  }
  #pragma unroll
  for (int r=0;r<4;r++){
    if (!ok_[r]) continue;
    const float* wr = embWf + (size_t)wt_[r]*HDIM;
    int op = opos_[r];
    #pragma unroll
    for (int nt=0;nt<4;nt++){
      int col = nt*16 + c16;
      float v = sigf(g4[nt][r] + wr[col]) * cc[r][nt];
      f16x2 o; o.x = hh[r][nt]; o.y = (f16)v;
      HFout[(size_t)op*HDIM + col] = o;
    }
  }
}

// ================= root =================
__global__ __launch_bounds__(256) void rootred_kernel(
    const f16x2* __restrict__ HFin, float* __restrict__ rootacc)
{
  int t = blockIdx.x*blockDim.x + threadIdx.x;
  int m = t & 63;
  int j0 = t >> 6;
  int jstep = (gridDim.x*blockDim.x) >> 6;
  float af=0.f, ah=0.f;
  for (int j=j0; j<PER; j+=jstep){
    f16x2 v = HFin[(size_t)j*HDIM + m];
    ah += (float)v.x;
    af += (float)v.y;
  }
  __shared__ float red[256];
  red[threadIdx.x]=af; __syncthreads();
  if (threadIdx.x < 64) atomicAdd(&rootacc[m],    red[m]+red[64+m]+red[128+m]+red[192+m]);
  __syncthreads();
  red[threadIdx.x]=ah; __syncthreads();
  if (threadIdx.x < 64) atomicAdd(&rootacc[64+m], red[m]+red[64+m]+red[128+m]+red[192+m]);
}

__global__ void rootnode_kernel(
    const int* __restrict__ tok, const float* __restrict__ emb,
    const float* __restrict__ Wiou, const float* __restrict__ biou, const float* __restrict__ Uiou,
    const float* __restrict__ rootacc, float* __restrict__ out)
{
  int m = threadIdx.x;
  if (m >= HDIM) return;
  int t = tok[0];
  float ai=biou[m], ao=biou[HDIM+m], au=biou[2*HDIM+m];
  for (int e=0;e<EDIM;e++){
    float xe = emb[(size_t)t*EDIM+e];
    ai += Wiou[(size_t)m*EDIM+e]*xe;
    ao += Wiou[(size_t)(HDIM+m)*EDIM+e]*xe;
    au += Wiou[(size_t)(2*HDIM+m)*EDIM+e]*xe;
  }
  for (int k=0;k<HDIM;k++){
    float hv = rootacc[64+k];
    ai += Uiou[(size_t)m*HDIM+k]*hv;
    ao += Uiou[(size_t)(HDIM+m)*HDIM+k]*hv;
    au += Uiou[(size_t)(2*HDIM+m)*HDIM+k]*hv;
  }
  float c = sigf(ai)*tanh_f(au) + rootacc[m];
  out[m] = sigf(ao)*tanh_f(c);
}

// ================= launch =================
static inline char* alignup(char* p){
  uintptr_t u = (uintptr_t)p;
  u = (u + 255) & ~(uintptr_t)255;
  return (char*)u;
}

extern "C" void kernel_launch(void* const* d_in, const int* in_sizes, int n_in,
                              void* d_out, int out_size, void* d_ws, size_t ws_size,
                              hipStream_t stream)
{
  const int*   tok    = (const int*)d_in[0];
  const int*   parent = (const int*)d_in[1];
  const float* emb    = (const float*)d_in[4];
  const float* Wiou   = (const float*)d_in[5];
  const float* biou   = (const float*)d_in[6];
  const float* Uiou   = (const float*)d_in[7];
  const float* Wf     = (const float*)d_in[8];
  const float* bf     = (const float*)d_in[9];
  const float* Uf     = (const float*)d_in[10];
  float* out = (float*)d_out;

  char* w = (char*)d_ws;
  f16x2* HFA     = (f16x2*)w;  w = alignup(w + (size_t)PER*HDIM*sizeof(f16x2));
  f16x2* HFB     = (f16x2*)w;  w = alignup(w + (size_t)PER*HDIM*sizeof(f16x2));
  f16*   Htmp    = (f16*)w;    w = alignup(w + (size_t)PER*HDIM*sizeof(f16));
  float* Ctmp    = (float*)w;  w = alignup(w + (size_t)PER*HDIM*sizeof(float));
  int*   cnt     = (int*)w;    w = alignup(w + (size_t)NN*sizeof(int));
  int*   off     = (int*)w;    w = alignup(w + (size_t)NN*sizeof(int));
  int*   cursor  = (int*)w;    w = alignup(w + (size_t)NN*sizeof(int));
  int*   childpos= (int*)w;    w = alignup(w + (size_t)NN*sizeof(int));
  int*   ptok    = (int*)w;    w = alignup(w + (size_t)NN*sizeof(int));
  int*   bsum    = (int*)w;    w = alignup(w + 1024*sizeof(int));
  int*   bbase   = (int*)w;    w = alignup(w + 1024*sizeof(int));
  float* embWiou = (float*)w;  w = alignup(w + 1024*NIOU*sizeof(float));
  float* embWf   = (float*)w;  w = alignup(w + 1024*HDIM*sizeof(float));
  float* rootacc = (float*)w;  w = alignup(w + 128*sizeof(float));
  f16*   Ufpack  = (f16*)w;    w = alignup(w + 2*4*64*8*sizeof(f16));
  f16*   Biopack = (f16*)w;    w = alignup(w + 2*12*64*8*sizeof(f16));

  const int gPER = (PER + 255)/256;       // 586
  const int gALL = (6*PER + 255)/256;     // 3511

  hipMemsetAsync(cnt, 0, (size_t)(1 + 6*PER)*sizeof(int), stream);
  hipMemsetAsync(rootacc, 0, 128*sizeof(float), stream);

  countAll_kernel  <<<gALL, 256, 0, stream>>>(parent, cnt);
  scan1_kernel     <<<1024, 256, 0, stream>>>(cnt, bsum);
  scan2_kernel     <<<1, 1024, 0, stream>>>(bsum, bbase);
  scan3_kernel     <<<1024, 256, 0, stream>>>(cnt, bbase, off, cursor);
  scatterAll_kernel<<<gALL, 256, 0, stream>>>(parent, tok, cursor, childpos, ptok);
  tablepack_kernel <<<1025, 256, 0, stream>>>(emb, Wiou, biou, Wf, bf, Uf, Uiou,
                                              embWiou, embWf, Ufpack, Biopack);

  // leaf level: rel positions [0,PER), buffer A
  leafA_kernel<<<(PER*16 + 255)/256, 256, 0, stream>>>(tok, childpos, embWiou, Htmp, HFA, Ctmp);
  leafB_kernel<<<gPER, 256, 0, stream>>>(ptok, embWf, Ufpack, Htmp, Ctmp, HFA);

  // levels d=6..1
  f16x2* HFin = HFA; f16x2* HFou = HFB;
  for (int d=6; d>=1; --d){
    int poff = 1 + (d-1)*PER;
    node_fused<<<(PER + 63)/64, 256, 0, stream>>>(tok, off, childpos, ptok,
                                                  embWiou, embWf, Biopack, Ufpack,
                                                  HFin, HFou,
                                                  poff, d*PER, (d-1)*PER, (d==1) ? 1 : 0);
    f16x2* th=HFin; HFin=HFou; HFou=th;
  }

  // root: children are level-1 nodes at rel positions [0,PER)
  rootred_kernel<<<256, 256, 0, stream>>>(HFin, rootacc);
  rootnode_kernel<<<1, 64, 0, stream>>>(tok, emb, Wiou, biou, Uiou, rootacc, out);
}